// Round 1
// baseline (699.331 us; speedup 1.0000x reference)
//
#include <hip/hip_runtime.h>

constexpr float kAlpha = 0.1f;
constexpr float kBeta  = 1.1f;
constexpr int   kC     = 16;
constexpr int   kD     = 512;
constexpr float kEps   = 1e-8f;

// ws layout (float offsets)
constexpr int SUMS_OFF = 0;       // kC*kD = 8192 floats
constexpr int CNT_OFF  = 8192;    // 16
constexpr int TOT_OFF  = 8208;    // 1
constexpr int CN_OFF   = 8224;    // 8192 (16B aligned)
constexpr int MSK_OFF  = 16416;   // 16 (unsigned)
constexpr int SCL_OFF  = 16432;   // [0]=denom, [1]=num_pairs
constexpr int ZERO_FLOATS = 8209; // sums + cnt + total

__device__ __forceinline__ float dot4(float4 a, float4 b) {
    return a.x * b.x + a.y * b.y + a.z * b.z + a.w * b.w;
}

// ---------------------------------------------------------------- K1: class sums + counts
// Wave per row. Label is wave-uniform -> readfirstlane makes the LDS
// accumulator base scalar; accumulate via native ds_add_f32 (atomicAdd on
// LDS float). LDS layout is component-planar: idx(c,half,k,lane) =
// c*512 + half*256 + k*64 + lane, so every ds_add hits bank lane%32
// (2-way = free). Kills the 16-way cndmask select entirely.
// VGPR ~32 -> with 32KB LDS, 4 blocks/CU = 32 waves/CU.
__global__ __launch_bounds__(512) void k1_sums(const float* __restrict__ emb,
                                               const int* __restrict__ labels,
                                               float* __restrict__ sums,
                                               float* __restrict__ cnt,
                                               int N, int rpb) {
    __shared__ float lacc[kC * kD];   // 32 KB
    __shared__ float lcnt[kC];
    int tid = threadIdx.x;
    int wave = tid >> 6, lane = tid & 63;

    for (int i = tid; i < kC * kD; i += 512) lacc[i] = 0.f;
    if (tid < kC) lcnt[tid] = 0.f;
    __syncthreads();

    const float4* e4 = (const float4*)emb;
    int r0 = blockIdx.x * rpb;
    int r1 = min(r0 + rpb, N);

    // unroll x2: rows r and r+8 per iteration (8 waves -> 16 rows/block-iter)
    for (int r = r0 + wave; r < r1; r += 16) {
        int rb = r + 8;
        bool vb = rb < r1;
        int rbi = vb ? rb : r;

        float4 a0 = e4[(size_t)r * 128 + lane];
        float4 a1 = e4[(size_t)r * 128 + 64 + lane];
        float4 b0 = e4[(size_t)rbi * 128 + lane];
        float4 b1 = e4[(size_t)rbi * 128 + 64 + lane];
        int la = __builtin_amdgcn_readfirstlane(labels[r]);
        int lb = __builtin_amdgcn_readfirstlane(labels[rbi]);

        float* pa = &lacc[la * kD];
        atomicAdd(&pa[      lane], a0.x);
        atomicAdd(&pa[ 64 + lane], a0.y);
        atomicAdd(&pa[128 + lane], a0.z);
        atomicAdd(&pa[192 + lane], a0.w);
        atomicAdd(&pa[256 + lane], a1.x);
        atomicAdd(&pa[320 + lane], a1.y);
        atomicAdd(&pa[384 + lane], a1.z);
        atomicAdd(&pa[448 + lane], a1.w);
        if (lane == 0) atomicAdd(&lcnt[la], 1.f);

        if (vb) {
            float* pb = &lacc[lb * kD];
            atomicAdd(&pb[      lane], b0.x);
            atomicAdd(&pb[ 64 + lane], b0.y);
            atomicAdd(&pb[128 + lane], b0.z);
            atomicAdd(&pb[192 + lane], b0.w);
            atomicAdd(&pb[256 + lane], b1.x);
            atomicAdd(&pb[320 + lane], b1.y);
            atomicAdd(&pb[384 + lane], b1.z);
            atomicAdd(&pb[448 + lane], b1.w);
            if (lane == 0) atomicAdd(&lcnt[lb], 1.f);
        }
    }
    __syncthreads();

    // flush: iterate GLOBAL-coalesced; un-swizzle the planar LDS layout.
    // g = c*512 + half*256 + 4*l + k  <->  lds = c*512 + half*256 + k*64 + l
    for (int gidx = tid; gidx < kC * kD; gidx += 512) {
        int c = gidx >> 9;
        int d = gidx & 511;
        int half = d >> 8;
        int u = d & 255;
        int l = u >> 2, k = u & 3;
        atomicAdd(&sums[gidx], lacc[c * 512 + half * 256 + k * 64 + l]);
    }
    if (tid < kC) atomicAdd(&cnt[tid], lcnt[tid]);
}

// ---------------------------------------------------------------- K2: centroids, pair logic (1 block)
__global__ __launch_bounds__(256) void k2_cent(const float* __restrict__ sums,
                                               const float* __restrict__ cnt_g,
                                               float* __restrict__ cn_g,
                                               unsigned* __restrict__ mask_g,
                                               float* __restrict__ scal) {
    __shared__ __align__(16) float lcn[kC * kD];  // 32 KB
    __shared__ float lcnt[kC];
    __shared__ float red[256];
    __shared__ float norms[kC];
    __shared__ float pdm[kC * kC];
    int tid = threadIdx.x;
    if (tid < kC) lcnt[tid] = cnt_g[tid];
    __syncthreads();

    int c = tid >> 4, sub = tid & 15;
    float invc = 1.f / fmaxf(lcnt[c], 1.f);
    float sq = 0.f;
    for (int d = sub; d < kD; d += 16) {
        float v = sums[c * kD + d] * invc;
        lcn[c * kD + d] = v;
        sq += v * v;
    }
    red[tid] = sq;
    __syncthreads();
    if (tid < kC) {
        float t = 0.f;
        for (int k = 0; k < 16; ++k) t += red[tid * 16 + k];
        norms[tid] = fmaxf(sqrtf(t), kEps);
    }
    __syncthreads();
    for (int i = tid; i < kC * kD; i += 256) {
        float v = lcn[i] / norms[i / kD];
        lcn[i] = v;
        cn_g[i] = v;
    }
    __syncthreads();
    int pi = tid >> 4, pj = tid & 15;
    float dot = 0.f;
    for (int dd = 0; dd < kD; ++dd) {
        int d = (dd + tid) & (kD - 1);
        dot += lcn[pi * kD + d] * lcn[pj * kD + d];
    }
    pdm[tid] = 1.f - dot;
    __syncthreads();
    if (tid == 0) {
        unsigned m[kC];
        for (int a = 0; a < kC; ++a) m[a] = 0u;
        float npairs = 0.f;
        for (int a = 0; a < kC; ++a)
            for (int b = a + 1; b < kC; ++b) {
                bool close = (pdm[a * kC + b] <= kBeta) && (lcnt[a] > 0.f) && (lcnt[b] > 0.f);
                if (close) { m[a] |= 1u << b; m[b] |= 1u << a; npairs += 1.f; }
            }
        float count = 0.f;
        for (int a = 0; a < kC; ++a) {
            mask_g[a] = m[a];
            count += (float)__popc(m[a]) * lcnt[a];
        }
        scal[0] = fmaxf(count, 1.f);
        scal[1] = npairs;
    }
}

// ---------------------------------------------------------------- K3: main distance pass
// Centroids in registers (wreg[4][8]); embeddings loaded DIRECTLY from
// global (4-way broadcast within the wave -> same cacheline, one fetch).
// Each row is consumed by exactly one wave, so LDS staging had zero reuse:
// removed, along with both barriers. Depth-2 software pipeline: row B's
// loads are in flight while row A computes.
__global__ __launch_bounds__(512, 2) void k3_main(const float* __restrict__ emb,
                                                  const int* __restrict__ labels,
                                                  const float* __restrict__ cn_g,
                                                  const unsigned* __restrict__ mask_g,
                                                  float* __restrict__ total,
                                                  int N, int rpb) {
    __shared__ unsigned lmask[kC];
    __shared__ float wsum[8];
    int tid = threadIdx.x;
    int wave = tid >> 6, lane = tid & 63;
    int g = lane >> 4, j = lane & 15;

    // centroid fragment: class 4g+c, dims [64i+4j, 64i+4j+4)
    const float4* w4 = (const float4*)cn_g;
    float4 wreg[4][8];
#pragma unroll
    for (int c = 0; c < 4; ++c)
#pragma unroll
        for (int i = 0; i < 8; ++i)
            wreg[c][i] = w4[(4 * g + c) * 128 + i * 16 + j];
    if (tid < kC) lmask[tid] = mask_g[tid];
    __syncthreads();

    int r0 = blockIdx.x * rpb;
    int r1 = min(r0 + rpb, N);
    const float4* src = (const float4*)emb;
    float priv = 0.f;

#define K3_COMPUTE(X, LAB)                                                     \
    do {                                                                       \
        float d0 = 0.f, d1 = 0.f, d2 = 0.f, d3 = 0.f, nrm = 0.f;               \
        _Pragma("unroll")                                                      \
        for (int i = 0; i < 8; ++i) {                                          \
            float4 x = X[i];                                                   \
            nrm += dot4(x, x);                                                 \
            d0 += dot4(x, wreg[0][i]);                                         \
            d1 += dot4(x, wreg[1][i]);                                         \
            d2 += dot4(x, wreg[2][i]);                                         \
            d3 += dot4(x, wreg[3][i]);                                         \
        }                                                                      \
        _Pragma("unroll")                                                      \
        for (int m = 1; m < 16; m <<= 1) {                                     \
            d0 += __shfl_xor(d0, m, 64);                                       \
            d1 += __shfl_xor(d1, m, 64);                                       \
            d2 += __shfl_xor(d2, m, 64);                                       \
            d3 += __shfl_xor(d3, m, 64);                                       \
            nrm += __shfl_xor(nrm, m, 64);                                     \
        }                                                                      \
        if (j == 0) {                                                          \
            unsigned mm = lmask[LAB];                                          \
            float inv = 1.f / fmaxf(sqrtf(nrm), kEps);                         \
            float dv[4] = {d0, d1, d2, d3};                                    \
            float s = 0.f;                                                     \
            _Pragma("unroll")                                                  \
            for (int c = 0; c < 4; ++c) {                                      \
                int cg = 4 * g + c;                                            \
                float dd = 1.f - dv[c] * inv;                                  \
                if ((mm >> cg) & 1u) s += fmaxf(kBeta - dd, 0.f);              \
                if (cg == LAB) s += (float)__popc(mm) * fmaxf(dd - kAlpha, 0.f);\
            }                                                                  \
            priv += s;                                                         \
        }                                                                      \
    } while (0)

    int rA = r0 + wave;
    if (rA < r1) {
        float4 xA[8], xB[8];
        int laA, laB;
#pragma unroll
        for (int i = 0; i < 8; ++i) xA[i] = src[(size_t)rA * 128 + i * 16 + j];
        laA = labels[rA];
        int rB = rA + 8;
        while (true) {
            bool vB = rB < r1;
            int rBi = vB ? rB : rA;
#pragma unroll
            for (int i = 0; i < 8; ++i) xB[i] = src[(size_t)rBi * 128 + i * 16 + j];
            laB = labels[rBi];
            K3_COMPUTE(xA, laA);
            if (!vB) break;

            int rN = rB + 8;
            bool vN = rN < r1;
            int rNi = vN ? rN : rB;
#pragma unroll
            for (int i = 0; i < 8; ++i) xA[i] = src[(size_t)rNi * 128 + i * 16 + j];
            laA = labels[rNi];
            K3_COMPUTE(xB, laB);
            if (!vN) break;
            rA = rN;
            rB = rN + 8;
        }
    }
#undef K3_COMPUTE

    // block reduce
#pragma unroll
    for (int off = 32; off > 0; off >>= 1) priv += __shfl_down(priv, off, 64);
    if (lane == 0) wsum[wave] = priv;
    __syncthreads();
    if (tid == 0) {
        float t = 0.f;
#pragma unroll
        for (int w = 0; w < 8; ++w) t += wsum[w];
        atomicAdd(total, t);
    }
}

// ---------------------------------------------------------------- K4: epilogue
__global__ void k4_final(const float* __restrict__ total,
                         const float* __restrict__ scal,
                         float* __restrict__ out) {
    out[0] = (scal[1] > 0.f) ? (total[0] / scal[0]) : 0.f;
}

extern "C" void kernel_launch(void* const* d_in, const int* in_sizes, int n_in,
                              void* d_out, int out_size, void* d_ws, size_t ws_size,
                              hipStream_t stream) {
    const float* emb = (const float*)d_in[0];
    const int* labels = (const int*)d_in[1];
    int N = in_sizes[0] / kD;

    float* ws = (float*)d_ws;
    float* sums = ws + SUMS_OFF;
    float* cnt = ws + CNT_OFF;
    float* total = ws + TOT_OFF;
    float* cn = ws + CN_OFF;
    unsigned* mask = (unsigned*)(ws + MSK_OFF);
    float* scal = ws + SCL_OFF;

    hipMemsetAsync(d_ws, 0, ZERO_FLOATS * sizeof(float), stream);

    int blocks1 = 1024;                       // 4 blocks/CU (32KB LDS) -> full occupancy
    int rpb1 = (N + blocks1 - 1) / blocks1;
    k1_sums<<<blocks1, 512, 0, stream>>>(emb, labels, sums, cnt, N, rpb1);

    k2_cent<<<1, 256, 0, stream>>>(sums, cnt, cn, mask, scal);

    int blocks3 = 256;                        // 1 block/CU, 8 waves resident
    int rpb3 = (N + blocks3 - 1) / blocks3;
    k3_main<<<blocks3, 512, 0, stream>>>(emb, labels, cn, mask, total, N, rpb3);

    k4_final<<<1, 1, 0, stream>>>(total, scal, (float*)d_out);
}

// Round 2
// 558.981 us; speedup vs baseline: 1.2511x; 1.2511x over previous
//
#include <hip/hip_runtime.h>

constexpr float kAlpha = 0.1f;
constexpr float kBeta  = 1.1f;
constexpr int   kC     = 16;
constexpr int   kD     = 512;
constexpr float kEps   = 1e-8f;

// ws layout (float offsets)
constexpr int SUMS_OFF = 0;       // kC*kD = 8192
constexpr int CNT_OFF  = 8192;    // 16
constexpr int TOT_OFF  = 8208;    // 1
constexpr int CTR1_OFF = 8209;    // int: k1 completion counter
constexpr int CTR2_OFF = 8210;    // int: k3 completion counter
constexpr int FLAG_OFF = 8224;    // 512 ints: per-block "am I last" flag
constexpr int PDM_OFF  = 8960;    // 256 floats scratch (pair distances)
constexpr int CN_OFF   = 9216;    // 8192 (16B aligned: 9216*4 % 16 == 0)
constexpr int MSK_OFF  = 17408;   // 16 unsigned
constexpr int SCL_OFF  = 17424;   // [0]=denom, [1]=num_pairs
constexpr int ZERO_FLOATS = 8211; // sums + cnt + total + ctr1 + ctr2

__device__ __forceinline__ float dot4(float4 a, float4 b) {
    return a.x * b.x + a.y * b.y + a.z * b.z + a.w * b.w;
}

// ---------------------------------------------------------------- K1: class sums + counts (+ fused centroid/pair epilogue)
// Wave per half-row. Label -> readfirstlane -> SGPR; per-class mask is a
// scalar select feeding v_fmac (4 VALU/class/row, half of round-0's
// cndmask form; SALU compare runs in parallel). Register-only inner loop,
// unroll-4 rows for 4KB/wave outstanding loads. Flush: barrier-staggered
// NON-atomic LDS merge (4 waves hit 4 disjoint classes per step), then
// coalesced global atomicAdd. Last block (atomic counter) runs the old k2.
__global__ __launch_bounds__(256) void k1_sums(const float* __restrict__ emb,
                                               const int* __restrict__ labels,
                                               float* __restrict__ ws,
                                               int N, int rpb) {
    __shared__ float lacc[kC * kD];   // exactly 32768 B -> 5 blocks/CU possible
    float* sums  = ws + SUMS_OFF;
    float* cnt_g = ws + CNT_OFF;
    float* cn_g  = ws + CN_OFF;
    float* pdm_g = ws + PDM_OFF;
    float* scal  = ws + SCL_OFF;
    unsigned* mask_g = (unsigned*)(ws + MSK_OFF);
    int* ctr1 = (int*)(ws + CTR1_OFF);
    int* flag = (int*)(ws + FLAG_OFF);

    int tid = threadIdx.x;
    int wave = tid >> 6, lane = tid & 63;
    int half = wave & 1, strm = wave >> 1;   // 2 row-streams x 2 halves

    for (int i = tid; i < kC * kD; i += 256) lacc[i] = 0.f;

    float4 acc[kC];
#pragma unroll
    for (int c = 0; c < kC; ++c) acc[c] = make_float4(0.f, 0.f, 0.f, 0.f);
    float cacc = 0.f;

    const float4* e4 = (const float4*)emb;
    int r0 = blockIdx.x * rpb;
    int r1 = min(r0 + rpb, N);
    const int o = half * 64 + lane;

    for (int base = r0 + strm; base < r1; base += 8) {
        int rA = base;
        int rB = base + 2, rC = base + 4, rD = base + 6;
        int cB = rB < r1 ? rB : rA;
        int cC = rC < r1 ? rC : rA;
        int cD = rD < r1 ? rD : rA;
        float4 xA = e4[(size_t)rA * 128 + o];
        float4 xB = e4[(size_t)cB * 128 + o];
        float4 xC = e4[(size_t)cC * 128 + o];
        float4 xD = e4[(size_t)cD * 128 + o];
        int laA = __builtin_amdgcn_readfirstlane(labels[rA]);
        int laB = rB < r1 ? __builtin_amdgcn_readfirstlane(labels[cB]) : -1;
        int laC = rC < r1 ? __builtin_amdgcn_readfirstlane(labels[cC]) : -1;
        int laD = rD < r1 ? __builtin_amdgcn_readfirstlane(labels[cD]) : -1;
#pragma unroll
        for (int c = 0; c < kC; ++c) {
            float mA = (laA == c) ? 1.f : 0.f;   // SALU select (la is SGPR)
            float mB = (laB == c) ? 1.f : 0.f;
            float mC = (laC == c) ? 1.f : 0.f;
            float mD = (laD == c) ? 1.f : 0.f;
            acc[c].x += mA * xA.x; acc[c].y += mA * xA.y; acc[c].z += mA * xA.z; acc[c].w += mA * xA.w;
            acc[c].x += mB * xB.x; acc[c].y += mB * xB.y; acc[c].z += mB * xB.z; acc[c].w += mB * xB.w;
            acc[c].x += mC * xC.x; acc[c].y += mC * xC.y; acc[c].z += mC * xC.z; acc[c].w += mC * xC.w;
            acc[c].x += mD * xD.x; acc[c].y += mD * xD.y; acc[c].z += mD * xD.z; acc[c].w += mD * xD.w;
        }
        if (half == 0) {
            cacc += ((laA == lane) ? 1.f : 0.f) + ((laB == lane) ? 1.f : 0.f)
                  + ((laC == lane) ? 1.f : 0.f) + ((laD == lane) ? 1.f : 0.f);
        }
    }

    // ---- flush: staggered non-atomic LDS merge (planar layout: c*512 + half*256 + comp*64 + lane)
    __syncthreads();
#pragma unroll 1
    for (int s = 0; s < kC; ++s) {
        int c = (s + wave * 4) & 15;          // 4 waves -> 4 disjoint classes per step
        float* p = &lacc[c * kD + half * 256 + lane];
        float4 a = acc[c];
        p[0]   += a.x;
        p[64]  += a.y;
        p[128] += a.z;
        p[192] += a.w;
        __syncthreads();
    }

    // global flush, coalesced in sums-linear order (unswizzle planar)
    for (int g = tid; g < kC * kD; g += 256) {
        int c = g >> 9, d = g & 511;
        int hh = d >> 8, u = d & 255;
        int l = u >> 2, k = u & 3;
        atomicAdd(&sums[g], lacc[c * kD + hh * 256 + k * 64 + l]);
    }
    if (half == 0 && lane < kC) atomicAdd(&cnt_g[lane], cacc);

    // ---- completion counter; last block runs centroid/pair logic
    __threadfence();
    __syncthreads();
    if (tid == 0) {
        int old = atomicAdd(ctr1, 1);
        flag[blockIdx.x] = (old == (int)gridDim.x - 1) ? 1 : 0;
    }
    __syncthreads();
    if (flag[blockIdx.x] == 0) return;   // same-CU L1: coherent within block
    __threadfence();                     // acquire before reading other blocks' sums

    // ===== k2 phase (one block, 256 threads) =====
    int c = tid >> 4, sub = tid & 15;
    float cntc = atomicAdd(&cnt_g[c], 0.f);      // coherent read of atomic data
    float invc = 1.f / fmaxf(cntc, 1.f);
    float sq = 0.f;
    for (int d = sub; d < kD; d += 16) {
        float v = atomicAdd(&sums[c * kD + d], 0.f) * invc;
        lacc[c * kD + d] = v;                    // reuse lacc as centroid buffer
        sq += v * v;
    }
#pragma unroll
    for (int m = 1; m < 16; m <<= 1) sq += __shfl_xor(sq, m, 64);  // 16-groups are wave-aligned
    float inv = 1.f / fmaxf(sqrtf(sq), kEps);
    for (int d = sub; d < kD; d += 16) {
        float v = lacc[c * kD + d] * inv;
        lacc[c * kD + d] = v;
        cn_g[c * kD + d] = v;
    }
    __syncthreads();

    int pi = tid >> 4, pj = tid & 15;
    float dot = 0.f;
    for (int dd = 0; dd < kD; ++dd) {
        int d = (dd + tid) & (kD - 1);
        dot += lacc[pi * kD + d] * lacc[pj * kD + d];
    }
    pdm_g[tid] = 1.f - dot;
    __syncthreads();

    if (tid == 0) {
        float lc[kC];
        for (int a = 0; a < kC; ++a) lc[a] = atomicAdd(&cnt_g[a], 0.f);
        unsigned m[kC];
        for (int a = 0; a < kC; ++a) m[a] = 0u;
        float npairs = 0.f;
        for (int a = 0; a < kC; ++a)
            for (int b = a + 1; b < kC; ++b) {
                bool close = (pdm_g[a * kC + b] <= kBeta) && (lc[a] > 0.f) && (lc[b] > 0.f);
                if (close) { m[a] |= 1u << b; m[b] |= 1u << a; npairs += 1.f; }
            }
        float count = 0.f;
        for (int a = 0; a < kC; ++a) {
            mask_g[a] = m[a];
            count += (float)__popc(m[a]) * lc[a];
        }
        scal[0] = fmaxf(count, 1.f);
        scal[1] = npairs;
    }
}

// ---------------------------------------------------------------- K3: main distance pass (+ fused final epilogue)
// Centroids in registers (wreg[4][8]); embeddings loaded DIRECTLY from
// global (4-way broadcast within the wave -> same cacheline, one fetch).
// Depth-2 software pipeline, no barriers in the main loop. Last block
// (atomic counter) computes the final scalar.
__global__ __launch_bounds__(512, 2) void k3_main(const float* __restrict__ emb,
                                                  const int* __restrict__ labels,
                                                  float* __restrict__ ws,
                                                  float* __restrict__ out,
                                                  int N, int rpb) {
    __shared__ unsigned lmask[kC];
    __shared__ float wsum[8];
    const float* cn_g = ws + CN_OFF;
    const unsigned* mask_g = (const unsigned*)(ws + MSK_OFF);
    float* total = ws + TOT_OFF;
    const float* scal = ws + SCL_OFF;
    int* ctr2 = (int*)(ws + CTR2_OFF);

    int tid = threadIdx.x;
    int wave = tid >> 6, lane = tid & 63;
    int g = lane >> 4, j = lane & 15;

    const float4* w4 = (const float4*)cn_g;
    float4 wreg[4][8];
#pragma unroll
    for (int c = 0; c < 4; ++c)
#pragma unroll
        for (int i = 0; i < 8; ++i)
            wreg[c][i] = w4[(4 * g + c) * 128 + i * 16 + j];
    if (tid < kC) lmask[tid] = mask_g[tid];
    __syncthreads();

    int r0 = blockIdx.x * rpb;
    int r1 = min(r0 + rpb, N);
    const float4* src = (const float4*)emb;
    float priv = 0.f;

#define K3_COMPUTE(X, LAB)                                                     \
    do {                                                                       \
        float d0 = 0.f, d1 = 0.f, d2 = 0.f, d3 = 0.f, nrm = 0.f;               \
        _Pragma("unroll")                                                      \
        for (int i = 0; i < 8; ++i) {                                          \
            float4 x = X[i];                                                   \
            nrm += dot4(x, x);                                                 \
            d0 += dot4(x, wreg[0][i]);                                         \
            d1 += dot4(x, wreg[1][i]);                                         \
            d2 += dot4(x, wreg[2][i]);                                         \
            d3 += dot4(x, wreg[3][i]);                                         \
        }                                                                      \
        _Pragma("unroll")                                                      \
        for (int m = 1; m < 16; m <<= 1) {                                     \
            d0 += __shfl_xor(d0, m, 64);                                       \
            d1 += __shfl_xor(d1, m, 64);                                       \
            d2 += __shfl_xor(d2, m, 64);                                       \
            d3 += __shfl_xor(d3, m, 64);                                       \
            nrm += __shfl_xor(nrm, m, 64);                                     \
        }                                                                      \
        if (j == 0) {                                                          \
            unsigned mm = lmask[LAB];                                          \
            float inv = 1.f / fmaxf(sqrtf(nrm), kEps);                         \
            float dv[4] = {d0, d1, d2, d3};                                    \
            float s = 0.f;                                                     \
            _Pragma("unroll")                                                  \
            for (int c = 0; c < 4; ++c) {                                      \
                int cg = 4 * g + c;                                            \
                float dd = 1.f - dv[c] * inv;                                  \
                if ((mm >> cg) & 1u) s += fmaxf(kBeta - dd, 0.f);              \
                if (cg == LAB) s += (float)__popc(mm) * fmaxf(dd - kAlpha, 0.f);\
            }                                                                  \
            priv += s;                                                         \
        }                                                                      \
    } while (0)

    int rA = r0 + wave;
    if (rA < r1) {
        float4 xA[8], xB[8];
        int laA, laB;
#pragma unroll
        for (int i = 0; i < 8; ++i) xA[i] = src[(size_t)rA * 128 + i * 16 + j];
        laA = labels[rA];
        int rB = rA + 8;
        while (true) {
            bool vB = rB < r1;
            int rBi = vB ? rB : rA;
#pragma unroll
            for (int i = 0; i < 8; ++i) xB[i] = src[(size_t)rBi * 128 + i * 16 + j];
            laB = labels[rBi];
            K3_COMPUTE(xA, laA);
            if (!vB) break;

            int rN = rB + 8;
            bool vN = rN < r1;
            int rNi = vN ? rN : rB;
#pragma unroll
            for (int i = 0; i < 8; ++i) xA[i] = src[(size_t)rNi * 128 + i * 16 + j];
            laA = labels[rNi];
            K3_COMPUTE(xB, laB);
            if (!vN) break;
            rA = rN;
            rB = rN + 8;
        }
    }
#undef K3_COMPUTE

    // block reduce
#pragma unroll
    for (int off = 32; off > 0; off >>= 1) priv += __shfl_down(priv, off, 64);
    if (lane == 0) wsum[wave] = priv;
    __syncthreads();
    if (tid == 0) {
        float t = 0.f;
#pragma unroll
        for (int w = 0; w < 8; ++w) t += wsum[w];
        atomicAdd(total, t);
        __threadfence();
        int old = atomicAdd(ctr2, 1);
        if (old == (int)gridDim.x - 1) {
            float tot = atomicAdd(total, 0.f);   // coherent read
            out[0] = (scal[1] > 0.f) ? (tot / scal[0]) : 0.f;
        }
    }
}

extern "C" void kernel_launch(void* const* d_in, const int* in_sizes, int n_in,
                              void* d_out, int out_size, void* d_ws, size_t ws_size,
                              hipStream_t stream) {
    const float* emb = (const float*)d_in[0];
    const int* labels = (const int*)d_in[1];
    int N = in_sizes[0] / kD;

    float* ws = (float*)d_ws;
    hipMemsetAsync(d_ws, 0, ZERO_FLOATS * sizeof(float), stream);

    int blocks1 = 512;
    int rpb1 = (N + blocks1 - 1) / blocks1;
    k1_sums<<<blocks1, 256, 0, stream>>>(emb, labels, ws, N, rpb1);

    int blocks3 = 256;
    int rpb3 = (N + blocks3 - 1) / blocks3;
    k3_main<<<blocks3, 512, 0, stream>>>(emb, labels, ws, (float*)d_out, N, rpb3);
}